// Round 15
// baseline (189.408 us; speedup 1.0000x reference)
//
#include <hip/hip_runtime.h>
#include <hip/hip_bf16.h>
#include <cstddef>

#define BIGV 10000000.0f
#define WPV  1.0f

#define BATCH 8
#define T1N 256
#define T2N 1024
#define CN 128
#define DN 1279          // T1+T2-1

#define RPB 16           // rows per ring block (16 KB)
#define NSLOT 4          // ring slots (64 KB LDS)
#define SLOT_BYTES (RPB * 1024)

// ---------------------------------------------------------------------------
// Kernel 1: skewed cost, R14 XOR-swizzled version (unchanged — its counters
// should finally surface this round once dp drops below it).
// ---------------------------------------------------------------------------
__global__ __launch_bounds__(256) void cost_kernel(const float* __restrict__ A,
                                                   const float* __restrict__ Bf,
                                                   const int* __restrict__ lenA,
                                                   const int* __restrict__ lenB,
                                                   float* __restrict__ sk) {
    __shared__ float As[64 * 64];     // 16,384 B
    __shared__ float Bs[127 * 64];    // 32,512 B

    const int b  = blockIdx.z;
    const int d0 = blockIdx.y * 64;
    const int j0 = blockIdx.x * 64;
    const int tid = threadIdx.x;

    const int dEnd = lenA[b] + lenB[b] - 2;
    if (d0 > dEnd) return;            // rows never consumed pre-latch

    const float* Ab = A  + (size_t)b * T1N * CN;
    const float* Bb = Bf + (size_t)b * T2N * CN;

    const int tj = tid & 15;
    const int td = tid >> 4;
    const int brow0 = td - tj + 63;   // in [48,66]
    const int rbase = d0 - j0 - 63;

    float acc[4][4];
    #pragma unroll
    for (int i = 0; i < 4; ++i)
        #pragma unroll
        for (int j = 0; j < 4; ++j) acc[i][j] = 0.0f;

#define SW(row, cq) (((row) << 6) + ((((cq) + (row)) & 15) << 2))

    for (int h = 0; h < 2; ++h) {
        const int ch0 = h * 64;
        #pragma unroll
        for (int i = 0; i < 4; ++i) {
            int idx = tid + i * 256;
            int row = idx >> 4;
            int cq  = idx & 15;
            float4 f = *(const float4*)(Ab + (size_t)(j0 + row) * CN + ch0 + (cq << 2));
            *(float4*)&As[SW(row, cq)] = f;
        }
        #pragma unroll
        for (int i = 0; i < 8; ++i) {
            int idx = tid + i * 256;
            if (idx < 2032) {                 // 127 rows x 16
                int row = idx >> 4;
                int cq  = idx & 15;
                int gr = rbase + row;
                gr = gr < 0 ? 0 : (gr > T2N - 1 ? T2N - 1 : gr);
                float4 f = *(const float4*)(Bb + (size_t)gr * CN + ch0 + (cq << 2));
                *(float4*)&Bs[SW(row, cq)] = f;
            }
        }
        __syncthreads();

        for (int cq = 0; cq < 16; ++cq) {
            float4 a4[4], bv[7];
            #pragma unroll
            for (int ji = 0; ji < 4; ++ji) {
                int row = tj + 16 * ji;
                a4[ji] = *(const float4*)&As[SW(row, cq)];
            }
            #pragma unroll
            for (int m = 0; m < 7; ++m) {
                int row = brow0 + 16 * (m - 3);
                bv[m] = *(const float4*)&Bs[SW(row, cq)];
            }
            #pragma unroll
            for (int dk = 0; dk < 4; ++dk) {
                #pragma unroll
                for (int ji = 0; ji < 4; ++ji) {
                    float4 aa = a4[ji];
                    float4 bb = bv[dk - ji + 3];
                    acc[dk][ji] += fabsf(aa.x - bb.x) + fabsf(aa.y - bb.y)
                                 + fabsf(aa.z - bb.z) + fabsf(aa.w - bb.w);
                }
            }
        }
        __syncthreads();
    }
#undef SW

    #pragma unroll
    for (int dk = 0; dk < 4; ++dk) {
        int d = d0 + td + 16 * dk;
        if (d < DN) {
            size_t rowoff = ((size_t)b * DN + d) * T1N;
            #pragma unroll
            for (int ji = 0; ji < 4; ++ji) {
                int j = j0 + tj + 16 * ji;
                sk[rowoff + j] = acc[dk][ji] * (1.0f / 128.0f);
            }
        }
    }
}

// ---------------------------------------------------------------------------
// Kernel 2: dp, SINGLE WAVE self-feeding via global_load_lds DMA ring.
// R14 post-mortem: two-wave handoff (spin + acquire lag + DS-pipe sharing)
// serialized producer-period + consumer-period (~1890 cyc/block vs ~900
// modeled). One wave now issues its own DMA (intrinsic = side effect, the
// compiler cannot sink it; asm vmcnt + memory clobber orders the following
// ds_reads). Uniform issue: every iteration DMAs block k+3 (rows clamped),
// so at iteration-k top issued=(k+3)*16 loads and vmcnt(32) => block k
// landed. 4-slot 64 KB ring, ~3 blocks (~1200 cyc) of latency cover.
// ---------------------------------------------------------------------------
__global__ __launch_bounds__(64, 1) void dp_wave_kernel(const float* __restrict__ sk,
                                                        const int* __restrict__ lenA,
                                                        const int* __restrict__ lenB,
                                                        float* __restrict__ out) {
    __shared__ char ring[NSLOT * SLOT_BYTES];   // 64 KB

    const int b = blockIdx.x;
    const int L = threadIdx.x;

    const int la = __builtin_amdgcn_readfirstlane(lenA[b]);
    const int lb = __builtin_amdgcn_readfirstlane(lenB[b]);
    const int dEnd = la + lb - 2;                // in [638, 1278]
    const int kLast = dEnd >> 4;                 // >= 39

    const float* skbp = sk + (size_t)b * DN * T1N + (L << 2);

#define DMA_BLK(K) do {                                                     \
        char* _slot = ring + ((K) & (NSLOT - 1)) * SLOT_BYTES;              \
        const int _r0 = (K) * RPB;                                          \
        _Pragma("unroll")                                                   \
        for (int _r = 0; _r < RPB; ++_r) {                                  \
            int _row = _r0 + _r; _row = _row > DN - 1 ? DN - 1 : _row;      \
            __builtin_amdgcn_global_load_lds(                               \
                (const __attribute__((address_space(1))) void*)(skbp + (size_t)_row * T1N), \
                (__attribute__((address_space(3))) void*)(_slot + (_r << 10)), \
                16, 0, 0);                                                  \
        }                                                                   \
    } while (0)

    float v1_0 = BIGV, v1_1 = BIGV, v1_2 = BIGV, v1_3 = BIGV;
    float v2_0 = BIGV, v2_1 = BIGV, v2_2 = BIGV, v2_3 = BIGV;
    float p1_prev = (L == 0) ? 0.0f : BIGV;      // pcp0 boundary column

#define SHFL_UP1(SRC)                                                       \
    __int_as_float(__builtin_amdgcn_update_dpp(                             \
        __float_as_int(BIGV), __float_as_int(SRC),                          \
        0x138 /* wave_shr:1 */, 0xF, 0xF, false))

#define DP_STEP(C4) do {                                                    \
        float4 c = (C4);                                                    \
        float p1 = SHFL_UP1(v1_3);                                          \
        float p2 = p1_prev;                                                 \
        float n0 = c.x + fminf(p2,   fminf(v1_0, p1)   + WPV);              \
        float n1 = c.y + fminf(v2_0, fminf(v1_1, v1_0) + WPV);              \
        float n2 = c.z + fminf(v2_1, fminf(v1_2, v1_1) + WPV);              \
        float n3 = c.w + fminf(v2_2, fminf(v1_3, v1_2) + WPV);              \
        p1_prev = p1;                                                       \
        v2_0 = v1_0; v2_1 = v1_1; v2_2 = v1_2; v2_3 = v1_3;                 \
        v1_0 = n0;   v1_1 = n1;   v1_2 = n2;   v1_3 = n3;                   \
    } while (0)

#define DP_STEP_G(C4, R) do {                                               \
        float4 c = (C4);                                                    \
        float p1 = SHFL_UP1(v1_3);                                          \
        float p2 = p1_prev;                                                 \
        float n0 = c.x + fminf(p2,   fminf(v1_0, p1)   + WPV);              \
        float n1 = c.y + fminf(v2_0, fminf(v1_1, v1_0) + WPV);              \
        float n2 = c.z + fminf(v2_1, fminf(v1_2, v1_1) + WPV);              \
        float n3 = c.w + fminf(v2_2, fminf(v1_3, v1_2) + WPV);              \
        if ((R) <= rem) {                                                   \
            p1_prev = p1;                                                   \
            v2_0 = v1_0; v2_1 = v1_1; v2_2 = v1_2; v2_3 = v1_3;             \
            v1_0 = n0;   v1_1 = n1;   v1_2 = n2;   v1_3 = n3;               \
        }                                                                   \
    } while (0)

    // wait until <=32 DMA outstanding -> block k (and older) fully landed;
    // memory clobber also stops the compiler hoisting ds_reads above it
#define WAIT32() asm volatile("s_waitcnt vmcnt(32)" ::: "memory")

#define READ_BLK(K)                                                         \
        const char* slot = ring + ((K) & (NSLOT - 1)) * SLOT_BYTES;         \
        const float4* rp = (const float4*)(slot + (L << 4));                \
        float4 c0  = rp[0 * 64],  c1  = rp[1 * 64],  c2  = rp[2 * 64],  c3  = rp[3 * 64];  \
        float4 c4_ = rp[4 * 64],  c5  = rp[5 * 64],  c6  = rp[6 * 64],  c7  = rp[7 * 64];  \
        float4 c8  = rp[8 * 64],  c9  = rp[9 * 64],  c10 = rp[10 * 64], c11 = rp[11 * 64]; \
        float4 c12 = rp[12 * 64], c13 = rp[13 * 64], c14 = rp[14 * 64], c15 = rp[15 * 64]; \
        __builtin_amdgcn_sched_barrier(0);

    // prologue: 3 blocks (48 loads) in flight
    DMA_BLK(0); DMA_BLK(1); DMA_BLK(2);

    for (int k = 0; k < kLast; ++k) {
        WAIT32();                        // block k landed
        READ_BLK(k);
        DMA_BLK(k + 3);                  // uniform issue (rows clamped; junk
                                         // blocks > kLast land in dead slots)
        DP_STEP(c0);  DP_STEP(c1);  DP_STEP(c2);  DP_STEP(c3);
        DP_STEP(c4_); DP_STEP(c5);  DP_STEP(c6);  DP_STEP(c7);
        DP_STEP(c8);  DP_STEP(c9);  DP_STEP(c10); DP_STEP(c11);
        DP_STEP(c12); DP_STEP(c13); DP_STEP(c14); DP_STEP(c15);
    }

    {   // final block: steps 16*kLast .. dEnd
        const int rem = dEnd & 15;
        WAIT32();                        // block kLast landed (issued <= kLast+2 ahead)
        READ_BLK(kLast);
        DP_STEP_G(c0, 0);   DP_STEP_G(c1, 1);   DP_STEP_G(c2, 2);   DP_STEP_G(c3, 3);
        DP_STEP_G(c4_, 4);  DP_STEP_G(c5, 5);   DP_STEP_G(c6, 6);   DP_STEP_G(c7, 7);
        DP_STEP_G(c8, 8);   DP_STEP_G(c9, 9);   DP_STEP_G(c10, 10); DP_STEP_G(c11, 11);
        DP_STEP_G(c12, 12); DP_STEP_G(c13, 13); DP_STEP_G(c14, 14); DP_STEP_G(c15, 15);
    }

    // drain remaining DMA before endpgm
    asm volatile("s_waitcnt vmcnt(0)" ::: "memory");

    // loss_i = row dEnd at column la -> t = la-1, lane (la-1)>>2, slot (la-1)&3
    const int tcap = la - 1;
    if (L == (tcap >> 2)) {
        const int k = tcap & 3;
        float r = v1_0;
        if (k == 1) r = v1_1;
        else if (k == 2) r = v1_2;
        else if (k == 3) r = v1_3;
        atomicAdd(out, r);               // d_out zeroed via hipMemsetAsync
    }
#undef READ_BLK
#undef WAIT32
#undef DP_STEP_G
#undef DP_STEP
#undef SHFL_UP1
#undef DMA_BLK
}

extern "C" void kernel_launch(void* const* d_in, const int* in_sizes, int n_in,
                              void* d_out, int out_size, void* d_ws, size_t ws_size,
                              hipStream_t stream) {
    const float* feaA = (const float*)d_in[0];
    const int*   lenA = (const int*)d_in[1];
    const float* feaB = (const float*)d_in[2];
    const int*   lenB = (const int*)d_in[3];

    float* sk = (float*)d_ws;                                   // 8*1279*256*4 B

    hipMemsetAsync(d_out, 0, sizeof(float), stream);
    cost_kernel<<<dim3(T1N / 64, (DN + 63) / 64, BATCH), 256, 0, stream>>>(feaA, feaB, lenA, lenB, sk);
    dp_wave_kernel<<<BATCH, 64, 0, stream>>>(sk, lenA, lenB, (float*)d_out);
}

// Round 16
// 167.056 us; speedup vs baseline: 1.1338x; 1.1338x over previous
//
#include <hip/hip_runtime.h>
#include <hip/hip_bf16.h>
#include <cstddef>

#define BIGV 10000000.0f
#define WPV  1.0f

#define BATCH 8
#define T1N 256
#define T2N 1024
#define CN 128
#define DN 1279          // T1+T2-1

#define RPB 16           // rows per ring block (16 KB)
#define NSLOT 3          // ring slots
#define SLOT_BYTES (RPB * 1024)

// ---------------------------------------------------------------------------
// Kernel 1: skewed cost, R16: 128(d) x 64(j) tile, 8x4 micro-tile.
// vs R14 64x64: LDS reads/cell -32% (15 b128 per 32 cells), half the
// blocks (320), B rows staged once per 128 d-rows. XOR swizzle kept.
// LDS: As 16 KB + Bs 191x64x4 = 47.75 KB -> 63.75 KB, 2 blocks/CU.
// ---------------------------------------------------------------------------
__global__ __launch_bounds__(256) void cost_kernel(const float* __restrict__ A,
                                                   const float* __restrict__ Bf,
                                                   const int* __restrict__ lenA,
                                                   const int* __restrict__ lenB,
                                                   float* __restrict__ sk) {
    __shared__ float As[64 * 64];      // 16,384 B
    __shared__ float Bs[191 * 64];     // 48,896 B

    const int b  = blockIdx.z;
    const int d0 = blockIdx.y * 128;
    const int j0 = blockIdx.x * 64;
    const int tid = threadIdx.x;

    const int dEnd = lenA[b] + lenB[b] - 2;
    if (d0 > dEnd) return;             // rows never consumed pre-latch

    const float* Ab = A  + (size_t)b * T1N * CN;
    const float* Bb = Bf + (size_t)b * T2N * CN;

    const int tj = tid & 15;
    const int td = tid >> 4;
    const int brow0 = td - tj + 63;    // in [48,78]; r = brow0 + 16*(dk-ji) in [0,190]
    const int rbase = d0 - j0 - 63;    // global B row of local row 0

    float acc[8][4];
    #pragma unroll
    for (int i = 0; i < 8; ++i)
        #pragma unroll
        for (int j = 0; j < 4; ++j) acc[i][j] = 0.0f;

#define SW(row, cq) (((row) << 6) + ((((cq) + (row)) & 15) << 2))

    for (int h = 0; h < 2; ++h) {
        const int ch0 = h * 64;
        // stage A half: 64 rows x 16 float4 = 1024
        #pragma unroll
        for (int i = 0; i < 4; ++i) {
            int idx = tid + i * 256;
            int row = idx >> 4;
            int cq  = idx & 15;
            float4 f = *(const float4*)(Ab + (size_t)(j0 + row) * CN + ch0 + (cq << 2));
            *(float4*)&As[SW(row, cq)] = f;
        }
        // stage B half-window: 191 rows x 16 float4 = 3056
        #pragma unroll
        for (int i = 0; i < 12; ++i) {
            int idx = tid + i * 256;
            if (idx < 3056) {
                int row = idx >> 4;
                int cq  = idx & 15;
                int gr = rbase + row;
                gr = gr < 0 ? 0 : (gr > T2N - 1 ? T2N - 1 : gr);
                float4 f = *(const float4*)(Bb + (size_t)gr * CN + ch0 + (cq << 2));
                *(float4*)&Bs[SW(row, cq)] = f;
            }
        }
        __syncthreads();

        for (int cq = 0; cq < 16; ++cq) {
            float4 a4[4], bv[11];
            #pragma unroll
            for (int ji = 0; ji < 4; ++ji) {
                int row = tj + 16 * ji;
                a4[ji] = *(const float4*)&As[SW(row, cq)];
            }
            #pragma unroll
            for (int m = 0; m < 11; ++m) {     // dk-ji in [-3,7]
                int row = brow0 + 16 * (m - 3);
                bv[m] = *(const float4*)&Bs[SW(row, cq)];
            }
            #pragma unroll
            for (int dk = 0; dk < 8; ++dk) {
                #pragma unroll
                for (int ji = 0; ji < 4; ++ji) {
                    float4 aa = a4[ji];
                    float4 bb = bv[dk - ji + 3];
                    acc[dk][ji] += fabsf(aa.x - bb.x) + fabsf(aa.y - bb.y)
                                 + fabsf(aa.z - bb.z) + fabsf(aa.w - bb.w);
                }
            }
        }
        __syncthreads();
    }
#undef SW

    #pragma unroll
    for (int dk = 0; dk < 8; ++dk) {
        int d = d0 + td + 16 * dk;
        if (d < DN) {
            size_t rowoff = ((size_t)b * DN + d) * T1N;
            #pragma unroll
            for (int ji = 0; ji < 4; ++ji) {
                int j = j0 + tj + 16 * ji;
                sk[rowoff + j] = acc[dk][ji] * (1.0f / 128.0f);
            }
        }
    }
}

// ---------------------------------------------------------------------------
// Kernel 2: dp, two-wave producer/consumer (R14 verbatim — best measured).
// R15 post-mortem: single-wave DMA fails because SIInsertWaitcnts sees the
// wave's own global_load_lds aliasing its ds_reads and inserts vmcnt(0)
// drains every block. Two-wave split keeps the consumer vmem-free.
// ---------------------------------------------------------------------------
__global__ __launch_bounds__(128, 1) void dp_wave_kernel(const float* __restrict__ sk,
                                                         const int* __restrict__ lenA,
                                                         const int* __restrict__ lenB,
                                                         float* __restrict__ out) {
    __shared__ char ring[NSLOT * SLOT_BYTES];   // 48 KB
    __shared__ int prod_cnt;
    __shared__ int cons_cnt;

    const int b = blockIdx.x;
    if (threadIdx.x == 0) { prod_cnt = 0; cons_cnt = 0; }
    __syncthreads();

    const int wave = threadIdx.x >> 6;
    const int L = threadIdx.x & 63;

    const int la = __builtin_amdgcn_readfirstlane(lenA[b]);
    const int lb = __builtin_amdgcn_readfirstlane(lenB[b]);
    const int dEnd = la + lb - 2;                // in [638, 1278]
    const int kLast = dEnd >> 4;
    const int nblk = kLast + 1;

    if (wave == 1) {
        const float* skbp = sk + (size_t)b * DN * T1N + (L << 2);
        for (int k = 0; k < nblk; ++k) {
            if (k >= NSLOT) {
                while (__hip_atomic_load(&cons_cnt, __ATOMIC_ACQUIRE,
                                         __HIP_MEMORY_SCOPE_WORKGROUP) < k - (NSLOT - 1))
                    __builtin_amdgcn_s_sleep(1);
            }
            char* slot = ring + (k % NSLOT) * SLOT_BYTES;
            const int r0 = k * RPB;
            #pragma unroll
            for (int r = 0; r < RPB; ++r) {
                int row = r0 + r; row = row > DN - 1 ? DN - 1 : row;
                __builtin_amdgcn_global_load_lds(
                    (const __attribute__((address_space(1))) void*)(skbp + (size_t)row * T1N),
                    (__attribute__((address_space(3))) void*)(slot + (r << 10)),
                    16, 0, 0);
            }
            asm volatile("s_waitcnt vmcnt(16)" ::: "memory");
            if (L == 0)
                __hip_atomic_store(&prod_cnt, k, __ATOMIC_RELEASE,
                                   __HIP_MEMORY_SCOPE_WORKGROUP);
        }
        asm volatile("s_waitcnt vmcnt(0)" ::: "memory");
        if (L == 0)
            __hip_atomic_store(&prod_cnt, nblk, __ATOMIC_RELEASE,
                               __HIP_MEMORY_SCOPE_WORKGROUP);
        return;
    }

    float v1_0 = BIGV, v1_1 = BIGV, v1_2 = BIGV, v1_3 = BIGV;
    float v2_0 = BIGV, v2_1 = BIGV, v2_2 = BIGV, v2_3 = BIGV;
    float p1_prev = (L == 0) ? 0.0f : BIGV;      // pcp0 boundary column

#define SHFL_UP1(SRC)                                                       \
    __int_as_float(__builtin_amdgcn_update_dpp(                             \
        __float_as_int(BIGV), __float_as_int(SRC),                          \
        0x138 /* wave_shr:1 */, 0xF, 0xF, false))

#define DP_STEP(C4) do {                                                    \
        float4 c = (C4);                                                    \
        float p1 = SHFL_UP1(v1_3);                                          \
        float p2 = p1_prev;                                                 \
        float n0 = c.x + fminf(p2,   fminf(v1_0, p1)   + WPV);              \
        float n1 = c.y + fminf(v2_0, fminf(v1_1, v1_0) + WPV);              \
        float n2 = c.z + fminf(v2_1, fminf(v1_2, v1_1) + WPV);              \
        float n3 = c.w + fminf(v2_2, fminf(v1_3, v1_2) + WPV);              \
        p1_prev = p1;                                                       \
        v2_0 = v1_0; v2_1 = v1_1; v2_2 = v1_2; v2_3 = v1_3;                 \
        v1_0 = n0;   v1_1 = n1;   v1_2 = n2;   v1_3 = n3;                   \
    } while (0)

#define DP_STEP_G(C4, R) do {                                               \
        float4 c = (C4);                                                    \
        float p1 = SHFL_UP1(v1_3);                                          \
        float p2 = p1_prev;                                                 \
        float n0 = c.x + fminf(p2,   fminf(v1_0, p1)   + WPV);              \
        float n1 = c.y + fminf(v2_0, fminf(v1_1, v1_0) + WPV);              \
        float n2 = c.z + fminf(v2_1, fminf(v1_2, v1_1) + WPV);              \
        float n3 = c.w + fminf(v2_2, fminf(v1_3, v1_2) + WPV);              \
        if ((R) <= rem) {                                                   \
            p1_prev = p1;                                                   \
            v2_0 = v1_0; v2_1 = v1_1; v2_2 = v1_2; v2_3 = v1_3;             \
            v1_0 = n0;   v1_1 = n1;   v1_2 = n2;   v1_3 = n3;               \
        }                                                                   \
    } while (0)

#define WAIT_BLK(K) do {                                                    \
        while (__hip_atomic_load(&prod_cnt, __ATOMIC_ACQUIRE,               \
                                 __HIP_MEMORY_SCOPE_WORKGROUP) < (K) + 1)   \
            __builtin_amdgcn_s_sleep(1);                                    \
    } while (0)

#define READ_BLK(K)                                                         \
        const char* slot = ring + ((K) % NSLOT) * SLOT_BYTES;               \
        const float4* rp = (const float4*)(slot + (L << 4));                \
        float4 c0  = rp[0 * 64],  c1  = rp[1 * 64],  c2  = rp[2 * 64],  c3  = rp[3 * 64];  \
        float4 c4_ = rp[4 * 64],  c5  = rp[5 * 64],  c6  = rp[6 * 64],  c7  = rp[7 * 64];  \
        float4 c8  = rp[8 * 64],  c9  = rp[9 * 64],  c10 = rp[10 * 64], c11 = rp[11 * 64]; \
        float4 c12 = rp[12 * 64], c13 = rp[13 * 64], c14 = rp[14 * 64], c15 = rp[15 * 64]; \
        __builtin_amdgcn_sched_barrier(0);

    for (int k = 0; k < kLast; ++k) {
        WAIT_BLK(k);
        READ_BLK(k);
        DP_STEP(c0);  DP_STEP(c1);  DP_STEP(c2);  DP_STEP(c3);
        DP_STEP(c4_); DP_STEP(c5);  DP_STEP(c6);  DP_STEP(c7);
        DP_STEP(c8);  DP_STEP(c9);  DP_STEP(c10); DP_STEP(c11);
        DP_STEP(c12); DP_STEP(c13); DP_STEP(c14); DP_STEP(c15);
        if (L == 0)
            __hip_atomic_store(&cons_cnt, k + 1, __ATOMIC_RELEASE,
                               __HIP_MEMORY_SCOPE_WORKGROUP);
    }

    {   // final block: steps 16*kLast .. dEnd
        const int rem = dEnd & 15;
        WAIT_BLK(kLast);
        READ_BLK(kLast);
        DP_STEP_G(c0, 0);   DP_STEP_G(c1, 1);   DP_STEP_G(c2, 2);   DP_STEP_G(c3, 3);
        DP_STEP_G(c4_, 4);  DP_STEP_G(c5, 5);   DP_STEP_G(c6, 6);   DP_STEP_G(c7, 7);
        DP_STEP_G(c8, 8);   DP_STEP_G(c9, 9);   DP_STEP_G(c10, 10); DP_STEP_G(c11, 11);
        DP_STEP_G(c12, 12); DP_STEP_G(c13, 13); DP_STEP_G(c14, 14); DP_STEP_G(c15, 15);
    }

    const int tcap = la - 1;
    if (L == (tcap >> 2)) {
        const int k = tcap & 3;
        float r = v1_0;
        if (k == 1) r = v1_1;
        else if (k == 2) r = v1_2;
        else if (k == 3) r = v1_3;
        atomicAdd(out, r);               // d_out zeroed via hipMemsetAsync
    }
#undef READ_BLK
#undef WAIT_BLK
#undef DP_STEP_G
#undef DP_STEP
#undef SHFL_UP1
}

extern "C" void kernel_launch(void* const* d_in, const int* in_sizes, int n_in,
                              void* d_out, int out_size, void* d_ws, size_t ws_size,
                              hipStream_t stream) {
    const float* feaA = (const float*)d_in[0];
    const int*   lenA = (const int*)d_in[1];
    const float* feaB = (const float*)d_in[2];
    const int*   lenB = (const int*)d_in[3];

    float* sk = (float*)d_ws;                                   // 8*1279*256*4 B

    hipMemsetAsync(d_out, 0, sizeof(float), stream);
    // 4 j-tiles x 10 d-tiles(128) x 8 batches = 320 blocks
    cost_kernel<<<dim3(T1N / 64, (DN + 127) / 128, BATCH), 256, 0, stream>>>(feaA, feaB, lenA, lenB, sk);
    dp_wave_kernel<<<BATCH, 128, 0, stream>>>(sk, lenA, lenB, (float*)d_out);
}